// Round 4
// baseline (4723.738 us; speedup 1.0000x reference)
//
#include <hip/hip_runtime.h>
#include <hip/hip_bf16.h>

typedef __attribute__((ext_vector_type(8))) short bf16x8;
typedef __attribute__((ext_vector_type(4))) float f32x4;

// ---------- helpers ----------
__device__ __forceinline__ short f2bf(float f) {
    union { __hip_bfloat16 h; short s; } u;
    u.h = __float2bfloat16(f);
    return u.s;
}

__device__ __forceinline__ void gld_lds16(const void* g, void* l) {
    auto gp = (const __attribute__((address_space(1))) void*)(g);
    auto lp = (__attribute__((address_space(3))) void*)(l);
    __builtin_amdgcn_global_load_lds(gp, lp, 16, 0, 0);
}

// read a 16B bf16x8 fragment from a swizzled 64x128B LDS tile
__device__ __forceinline__ bf16x8 ldfrag(const char* base, int row, int k /*bf16 idx*/) {
    int off = (row << 7) + (((k << 1)) ^ ((row & 7) << 4));
    return *(const bf16x8*)(base + off);
}

// ---------- transpose + fp32->bf16 convert:  in[R][C] f32  ->  out[C][R] bf16 ----------
__global__ __launch_bounds__(256) void tcvt(const float* __restrict__ in,
                                            __hip_bfloat16* __restrict__ out,
                                            int R, int C) {
    __shared__ float tile[64][65];
    const int r0 = blockIdx.x << 6, c0 = blockIdx.y << 6;
    const int tid = threadIdx.x;
    const int tr = tid >> 4, tc4 = (tid & 15) << 2;
#pragma unroll
    for (int it = 0; it < 4; ++it) {
        int row = (it << 4) + tr;
        const float4 vv = *(const float4*)(in + (size_t)(r0 + row) * C + c0 + tc4);
        tile[row][tc4 + 0] = vv.x;
        tile[row][tc4 + 1] = vv.y;
        tile[row][tc4 + 2] = vv.z;
        tile[row][tc4 + 3] = vv.w;
    }
    __syncthreads();
#pragma unroll
    for (int it = 0; it < 4; ++it) {
        int row = (it << 4) + tr;  // row in C-dim of output
        short4 o;
        o.x = f2bf(tile[tc4 + 0][row]);
        o.y = f2bf(tile[tc4 + 1][row]);
        o.z = f2bf(tile[tc4 + 2][row]);
        o.w = f2bf(tile[tc4 + 3][row]);
        *(short4*)((short*)out + (size_t)(c0 + row) * R + r0 + tc4) = o;
    }
}

// ---------- elementwise fp32->bf16 (no transpose) ----------
__global__ __launch_bounds__(256) void cvt4(const float* __restrict__ in,
                                            __hip_bfloat16* __restrict__ out, int n4) {
    int i = blockIdx.x * 256 + threadIdx.x;
    if (i < n4) {
        float4 vv = ((const float4*)in)[i];
        short4 o;
        o.x = f2bf(vv.x); o.y = f2bf(vv.y); o.z = f2bf(vv.z); o.w = f2bf(vv.w);
        ((short4*)out)[i] = o;
    }
}

// ---------- tiled bf16 MFMA GEMM: C[M][N] = A[M][K] @ Bt[N][K]^T ----------
// A-operand: direct global->VGPR (3 rotating slots, prefetch 2 iters ahead).
// B-operand: LDS-staged via global_load_lds, 4 buffers, XOR-swizzled, counted vmcnt.
// Issue-groups per iteration are pinned with sched_barrier(0) so the group-wise
// vmcnt arithmetic is valid regardless of intra-group scheduler reordering.
// NT = K/64 (compile-time -> full unroll, exact vmcnt literals).
// MODE 0: h0 epilogue  (bf16 out, ld 4096)
// MODE 1: RNN step     (out = relu(acc + v0*Win0[c] + v1*Win1[c]) -> bf16 G_t)
// MODE 2: decoder      (fp32 out, row r -> t=r>>8, b=r&255, out[b][t][p])
template <int MODE, int NT>
__global__ __launch_bounds__(256) void gemm_k(const __hip_bfloat16* __restrict__ A,
                                              const __hip_bfloat16* __restrict__ B,
                                              void* __restrict__ outp,
                                              const float* __restrict__ v,
                                              const float* __restrict__ Wi, int t) {
    __shared__ __align__(16) char lds[4][8192];  // B only: [buf][64 rows x 128B], swizzled
    const int id = blockIdx.x;
    int bm, bn;
    if constexpr (MODE == 2) {
        // 3200 blocks; chunk per XCD so the 8 bn-blocks sharing an A-slab stay on one XCD
        int xcd = id & 7, idx = id >> 3;
        int sw = xcd * 400 + idx;
        bm = sw >> 3;
        bn = sw & 7;
    } else {
        // 256 blocks; XCD k owns bn in [8k, 8k+8) -> W slab L2-resident across steps
        int xcd = id & 7, j = id >> 3;
        bn = (xcd << 3) + (j & 7);
        bm = j >> 3;
    }
    const int tid = threadIdx.x, wave = tid >> 6, lane = tid & 63;
    const int wr = wave >> 1, wc = wave & 1;

    const size_t rowB = (size_t)NT * 128;  // bytes per K-row
    // A fragment base: row = bm*64 + wr*32 + (lane&15), k-offset (lane>>4)*8 elems
    const char* Arow = (const char*)A +
                       (size_t)((bm << 6) + (wr << 5) + (lane & 15)) * rowB +
                       ((lane >> 4) << 4);

    f32x4 acc[2][2] = {};
    bf16x8 As[3][4];  // [slot][h*2+r] : h = k-half, r = row-block(+0/+16)

    auto stageB = [&](int buf, int kt) {
#pragma unroll
        for (int iss = 0; iss < 2; ++iss) {
            int p = (wave << 11) + (iss << 10) + (lane << 4);  // byte in 8KB tile
            int row = p >> 7;
            int kb = p & 127;
            int kbs = kb ^ ((row & 7) << 4);  // inverse-swizzled source column
            const char* gb = (const char*)B + (size_t)((bn << 6) + row) * rowB + kt * 128 + kbs;
            gld_lds16(gb, &lds[buf][(wave << 11) + (iss << 10)]);
        }
    };

    auto loadA = [&](int slot, int kt) {
        const char* p = Arow + (size_t)kt * 128;
        As[slot][0] = *(const bf16x8*)(p);                  // h0, rows +0
        As[slot][1] = *(const bf16x8*)(p + (rowB << 4));    // h0, rows +16
        As[slot][2] = *(const bf16x8*)(p + 64);             // h1, rows +0
        As[slot][3] = *(const bf16x8*)(p + (rowB << 4) + 64);
    };

    auto compute = [&](int slot, int buf) {
        const char* Bb = (const char*)lds[buf];
#pragma unroll
        for (int h = 0; h < 2; ++h) {
            int kloc = (h << 5) + ((lane >> 4) << 3);
            bf16x8 b0 = ldfrag(Bb, (wc << 5) + (lane & 15), kloc);
            bf16x8 b1 = ldfrag(Bb, (wc << 5) + 16 + (lane & 15), kloc);
            acc[0][0] = __builtin_amdgcn_mfma_f32_16x16x32_bf16(As[slot][h * 2], b0, acc[0][0], 0, 0, 0);
            acc[0][1] = __builtin_amdgcn_mfma_f32_16x16x32_bf16(As[slot][h * 2], b1, acc[0][1], 0, 0, 0);
            acc[1][0] = __builtin_amdgcn_mfma_f32_16x16x32_bf16(As[slot][h * 2 + 1], b0, acc[1][0], 0, 0, 0);
            acc[1][1] = __builtin_amdgcn_mfma_f32_16x16x32_bf16(As[slot][h * 2 + 1], b1, acc[1][1], 0, 0, 0);
        }
    };

    // prologue: pinned issue order [B0][A0][B1][A1][B2] = 14 outstanding.
    // sched_barrier(0) between pieces: without it the scheduler clusters the
    // plain A-loads ahead of the global_load_lds ops and the counted drains
    // below retire the wrong loads (round-3 NaN bug).
    stageB(0, 0);
    __builtin_amdgcn_sched_barrier(0);
    loadA(0, 0);
    __builtin_amdgcn_sched_barrier(0);
    stageB(1, 1);
    __builtin_amdgcn_sched_barrier(0);
    loadA(1, 1);
    __builtin_amdgcn_sched_barrier(0);
    stageB(2, 2);
    __builtin_amdgcn_sched_barrier(0);

#pragma unroll
    for (int kt = 0; kt < NT; ++kt) {
        // Drain through the issue-group containing B(kt): groups kt-2,kt-1
        // (each 4*A[kt+2<NT] + 2*B[kt+3<NT] ops) remain outstanding.
        const int nb = 4 + ((kt + 1 < NT) ? 6 : 0) + ((kt + 2 < NT) ? 2 : 0);
        asm volatile("s_waitcnt vmcnt(%0)" ::"i"(nb) : "memory");
        __builtin_amdgcn_s_barrier();
        __builtin_amdgcn_sched_barrier(0);  // pin group boundary
        compute(kt % 3, kt & 3);
        if (kt + 2 < NT) loadA((kt + 2) % 3, kt + 2);
        if (kt + 3 < NT) stageB((kt + 3) & 3, kt + 3);
    }

    const int rb = (bm << 6) + (wr << 5) + ((lane >> 4) << 2);
    const int cb = (bn << 6) + (wc << 5) + (lane & 15);

    if constexpr (MODE == 0) {
        __hip_bfloat16* O = (__hip_bfloat16*)outp;  // h0 [256][4096]
#pragma unroll
        for (int mf = 0; mf < 2; ++mf)
#pragma unroll
            for (int j = 0; j < 4; ++j) {
                int r = rb + mf * 16 + j;
#pragma unroll
                for (int nf = 0; nf < 2; ++nf) {
                    int c = cb + nf * 16;
                    union { __hip_bfloat16 h; short s; } u;
                    u.s = f2bf(acc[mf][nf][j]);
                    O[(size_t)r * 4096 + c] = u.h;
                }
            }
    } else if constexpr (MODE == 1) {
        __hip_bfloat16* O = (__hip_bfloat16*)outp;  // G_t [256][4096]
#pragma unroll
        for (int mf = 0; mf < 2; ++mf)
#pragma unroll
            for (int j = 0; j < 4; ++j) {
                int b = rb + mf * 16 + j;
                float v0 = v[(size_t)(b * 100 + t) * 2 + 0];
                float v1 = v[(size_t)(b * 100 + t) * 2 + 1];
#pragma unroll
                for (int nf = 0; nf < 2; ++nf) {
                    int c = cb + nf * 16;
                    float x = v0 * Wi[c] + v1 * Wi[4096 + c];
                    float val = fmaxf(acc[mf][nf][j] + x, 0.0f);
                    union { __hip_bfloat16 h; short s; } u;
                    u.s = f2bf(val);
                    O[(size_t)b * 4096 + c] = u.h;
                }
            }
    } else {
        float* O = (float*)outp;  // place_preds [256][100][512]
#pragma unroll
        for (int mf = 0; mf < 2; ++mf)
#pragma unroll
            for (int j = 0; j < 4; ++j) {
                int r = rb + mf * 16 + j;
                int tt = r >> 8;
                int b = r & 255;
#pragma unroll
                for (int nf = 0; nf < 2; ++nf) {
                    int c = cb + nf * 16;
                    O[((size_t)b * 100 + tt) * 512 + c] = acc[mf][nf][j];
                }
            }
    }
}

// ---------- launch ----------
extern "C" void kernel_launch(void* const* d_in, const int* in_sizes, int n_in,
                              void* d_out, int out_size, void* d_ws, size_t ws_size,
                              hipStream_t stream) {
    const float* v     = (const float*)d_in[0];  // [256][100][2]
    const float* P0    = (const float*)d_in[1];  // [256][512]
    const float* W_enc = (const float*)d_in[2];  // [512][4096]
    const float* W_in  = (const float*)d_in[3];  // [2][4096]
    const float* W_rec = (const float*)d_in[4];  // [4096][4096]
    const float* W_dec = (const float*)d_in[5];  // [4096][512]
    float* out = (float*)d_out;                  // [256][100][512]

    char* ws = (char*)d_ws;
    __hip_bfloat16* Wrt = (__hip_bfloat16*)(ws + 0);          // [4096][4096] = W_rec^T
    __hip_bfloat16* Wet = (__hip_bfloat16*)(ws + 33554432);   // [4096][512]  = W_enc^T
    __hip_bfloat16* Wdt = (__hip_bfloat16*)(ws + 37748736);   // [512][4096]  = W_dec^T
    __hip_bfloat16* P0b = (__hip_bfloat16*)(ws + 41943040);   // [256][512]
    __hip_bfloat16* h0  = (__hip_bfloat16*)(ws + 42205184);   // [256][4096]
    __hip_bfloat16* G   = (__hip_bfloat16*)(ws + 44302336);   // [100][256][4096]

    tcvt<<<dim3(64, 64), 256, 0, stream>>>(W_rec, Wrt, 4096, 4096);
    tcvt<<<dim3(8, 64), 256, 0, stream>>>(W_enc, Wet, 512, 4096);
    tcvt<<<dim3(64, 8), 256, 0, stream>>>(W_dec, Wdt, 4096, 512);
    cvt4<<<128, 256, 0, stream>>>(P0, P0b, 32768);

    // h0 = P0 @ W_enc
    gemm_k<0, 8><<<256, 256, 0, stream>>>(P0b, Wet, (void*)h0, nullptr, nullptr, 0);

    // recurrent steps
    for (int t = 0; t < 100; ++t) {
        const __hip_bfloat16* hprev = (t == 0) ? h0 : (G + (size_t)(t - 1) * 1048576);
        gemm_k<1, 64><<<256, 256, 0, stream>>>(hprev, Wrt,
                                               (void*)(G + (size_t)t * 1048576), v, W_in, t);
    }

    // decoder: [25600,4096] @ Wdt^T -> d_out
    gemm_k<2, 64><<<3200, 256, 0, stream>>>(G, Wdt, (void*)out, nullptr, nullptr, 0);
}

// Round 5
// 2656.921 us; speedup vs baseline: 1.7779x; 1.7779x over previous
//
#include <hip/hip_runtime.h>
#include <hip/hip_bf16.h>

typedef __attribute__((ext_vector_type(8))) short bf16x8;
typedef __attribute__((ext_vector_type(4))) float f32x4;

#define MFMA __builtin_amdgcn_mfma_f32_16x16x32_bf16

// ---------- helpers ----------
__device__ __forceinline__ short f2bf(float f) {
    union { __hip_bfloat16 h; short s; } u;
    u.h = __float2bfloat16(f);
    return u.s;
}

__device__ __forceinline__ void gld_lds16(const void* g, void* l) {
    auto gp = (const __attribute__((address_space(1))) void*)(g);
    auto lp = (__attribute__((address_space(3))) void*)(l);
    __builtin_amdgcn_global_load_lds(gp, lp, 16, 0, 0);
}

// read a 16B bf16x8 fragment from a swizzled 64x128B LDS tile
__device__ __forceinline__ bf16x8 ldfrag(const char* base, int row, int k /*bf16 idx*/) {
    int off = (row << 7) + (((k << 1)) ^ ((row & 7) << 4));
    return *(const bf16x8*)(base + off);
}

// ---------- transpose + fp32->bf16 convert:  in[R][C] f32  ->  out[C][R] bf16 ----------
__global__ __launch_bounds__(256) void tcvt(const float* __restrict__ in,
                                            __hip_bfloat16* __restrict__ out,
                                            int R, int C) {
    __shared__ float tile[64][65];
    const int r0 = blockIdx.x << 6, c0 = blockIdx.y << 6;
    const int tid = threadIdx.x;
    const int tr = tid >> 4, tc4 = (tid & 15) << 2;
#pragma unroll
    for (int it = 0; it < 4; ++it) {
        int row = (it << 4) + tr;
        const float4 vv = *(const float4*)(in + (size_t)(r0 + row) * C + c0 + tc4);
        tile[row][tc4 + 0] = vv.x;
        tile[row][tc4 + 1] = vv.y;
        tile[row][tc4 + 2] = vv.z;
        tile[row][tc4 + 3] = vv.w;
    }
    __syncthreads();
#pragma unroll
    for (int it = 0; it < 4; ++it) {
        int row = (it << 4) + tr;  // row in C-dim of output
        short4 o;
        o.x = f2bf(tile[tc4 + 0][row]);
        o.y = f2bf(tile[tc4 + 1][row]);
        o.z = f2bf(tile[tc4 + 2][row]);
        o.w = f2bf(tile[tc4 + 3][row]);
        *(short4*)((short*)out + (size_t)(c0 + row) * R + r0 + tc4) = o;
    }
}

// ---------- fp32 [R][C] -> MFMA-A-fragment-tiled bf16 ----------
// tile (r16, k32) = 16 rows x 32 cols, 1KB; lane l holds (row=l&15, k=(l>>4)*8+j)
// at byte tile*1024 + l*16 + j*2.  grid = (R/16)*(C/32) blocks of 64 threads.
__global__ __launch_bounds__(64) void cvt_tile(const float* __restrict__ in,
                                               __hip_bfloat16* __restrict__ out, int C) {
    const int kd32 = C >> 5;
    const int tile = blockIdx.x;
    const int r16 = tile / kd32, k32 = tile - r16 * kd32;
    const int l = threadIdx.x;
    const int row = (r16 << 4) + (l & 15);
    const int k0 = (k32 << 5) + ((l >> 4) << 3);
    const float* src = in + (size_t)row * C + k0;
    short o[8];
#pragma unroll
    for (int j = 0; j < 8; ++j) o[j] = f2bf(src[j]);
    *(bf16x8*)((char*)out + (size_t)tile * 1024 + (l << 4)) = *(bf16x8*)o;
}

// ---------- tiled bf16 MFMA GEMM: C[M][N] = A[M][K] @ Bt[N][K]^T ----------
// A: fragment-tiled layout, direct global->VGPR, 16 NAMED bf16x8 regs (4 slots),
//    3-deep prefetch. B: LDS 4-buffer via global_load_lds, XOR-swizzled.
// Uniform issue groups [2xB + 4xA] -> single literal vmcnt(12) steady state.
// MODE 0: h0 epilogue  (bf16 tiled out)
// MODE 1: RNN step     (relu(acc + v0*Wi0[c] + v1*Wi1[c]) -> bf16 tiled slab)
// MODE 2: decoder      (fp32 out, row r -> t=r>>8, b=r&255, out[b][t][p])
template <int MODE, int NT>
__global__ __launch_bounds__(256) void gemm_k(const __hip_bfloat16* __restrict__ A,
                                              const __hip_bfloat16* __restrict__ B,
                                              void* __restrict__ outp,
                                              const float* __restrict__ v,
                                              const float* __restrict__ Wi, int t) {
    __shared__ __align__(16) char lds[4][8192];  // B only: [buf][64 rows x 128B], swizzled
    const int id = blockIdx.x;
    int bm, bn;
    if constexpr (MODE == 2) {
        int xcd = id & 7, idx = id >> 3;
        int sw = xcd * 400 + idx;
        bm = sw >> 3;
        bn = sw & 7;
    } else {
        int xcd = id & 7, j = id >> 3;
        bn = (xcd << 3) + (j & 7);
        bm = j >> 3;
    }
    const int tid = threadIdx.x, wave = tid >> 6, lane = tid & 63;
    const int wr = wave >> 1, wc = wave & 1;

    const size_t rowB = (size_t)NT * 128;   // B bytes per K-row
    const size_t rstr = (size_t)NT * 2048;  // A bytes per r16-block (KD32*1024)
    // A tiled base: r16 = (bm*64 + wr*32)/16
    const char* pA = (const char*)A +
                     (size_t)(((bm << 6) + (wr << 5)) >> 4) * rstr + (lane << 4);

    f32x4 acc00 = {}, acc01 = {}, acc10 = {}, acc11 = {};
    bf16x8 A00, A01, A02, A03, A10, A11, A12, A13,
           A20, A21, A22, A23, A30, A31, A32, A33;

#define STAGEB(S, KT)                                                              \
    do {                                                                           \
        _Pragma("unroll") for (int iss = 0; iss < 2; ++iss) {                      \
            int p = (wave << 11) + (iss << 10) + (lane << 4);                      \
            int row_ = p >> 7;                                                     \
            int kb = p & 127;                                                      \
            int kbs = kb ^ ((row_ & 7) << 4);                                      \
            const char* gb =                                                       \
                (const char*)B + (size_t)((bn << 6) + row_) * rowB + (KT)*128 + kbs; \
            gld_lds16(gb, &lds[S][(wave << 11) + (iss << 10)]);                    \
        }                                                                          \
    } while (0)

#define LOADA(S, KT)                                          \
    do {                                                      \
        const char* _pa = pA + (size_t)(KT)*2048;             \
        A##S##0 = *(const bf16x8*)(_pa);                      \
        A##S##1 = *(const bf16x8*)(_pa + rstr);               \
        A##S##2 = *(const bf16x8*)(_pa + 1024);               \
        A##S##3 = *(const bf16x8*)(_pa + rstr + 1024);        \
    } while (0)

#define COMPUTE(S)                                                        \
    do {                                                                  \
        const char* Bb = (const char*)lds[S];                             \
        bf16x8 b0, b1;                                                    \
        b0 = ldfrag(Bb, (wc << 5) + (lane & 15), ((lane >> 4) << 3));     \
        b1 = ldfrag(Bb, (wc << 5) + 16 + (lane & 15), ((lane >> 4) << 3));\
        acc00 = MFMA(A##S##0, b0, acc00, 0, 0, 0);                        \
        acc01 = MFMA(A##S##0, b1, acc01, 0, 0, 0);                        \
        acc10 = MFMA(A##S##1, b0, acc10, 0, 0, 0);                        \
        acc11 = MFMA(A##S##1, b1, acc11, 0, 0, 0);                        \
        b0 = ldfrag(Bb, (wc << 5) + (lane & 15), 32 + ((lane >> 4) << 3));\
        b1 = ldfrag(Bb, (wc << 5) + 16 + (lane & 15),                     \
                    32 + ((lane >> 4) << 3));                             \
        acc00 = MFMA(A##S##2, b0, acc00, 0, 0, 0);                        \
        acc01 = MFMA(A##S##2, b1, acc01, 0, 0, 0);                        \
        acc10 = MFMA(A##S##3, b0, acc10, 0, 0, 0);                        \
        acc11 = MFMA(A##S##3, b1, acc11, 0, 0, 0);                        \
    } while (0)

// one pipeline iteration: drain to VM, barrier, compute slot C, issue group for KT+3 into slot SC
#define ITER(C, SC, VMLIT, DOISS, KT)                              \
    do {                                                           \
        asm volatile("s_waitcnt vmcnt(" #VMLIT ")" ::: "memory");  \
        __builtin_amdgcn_s_barrier();                              \
        __builtin_amdgcn_sched_barrier(0);                         \
        COMPUTE(C);                                                \
        if (DOISS) {                                               \
            STAGEB(SC, (KT) + 3);                                  \
            LOADA(SC, (KT) + 3);                                   \
        }                                                          \
    } while (0)

    // prologue: 3 pinned groups [B(j) A(j)], j=0..2 -> 18 outstanding
    STAGEB(0, 0); LOADA(0, 0);
    __builtin_amdgcn_sched_barrier(0);
    STAGEB(1, 1); LOADA(1, 1);
    __builtin_amdgcn_sched_barrier(0);
    STAGEB(2, 2); LOADA(2, 2);
    __builtin_amdgcn_sched_barrier(0);

    int kt = 0;
    for (; kt < NT - 4; kt += 4) {
        ITER(0, 3, 12, true, kt + 0);
        ITER(1, 0, 12, true, kt + 1);
        ITER(2, 1, 12, true, kt + 2);
        ITER(3, 2, 12, true, kt + 3);
    }
    // tail block: kt == NT-4
    ITER(0, 3, 12, true,  kt + 0);   // stages K-tile NT-1
    ITER(1, 0, 12, false, kt + 1);
    ITER(2, 1, 6,  false, kt + 2);
    ITER(3, 2, 0,  false, kt + 3);

#undef ITER
#undef COMPUTE
#undef LOADA
#undef STAGEB

    const int rb = (bm << 6) + (wr << 5) + ((lane >> 4) << 2);
    const int cb = (bn << 6) + (wc << 5) + (lane & 15);
    float accv[2][2][4];
#pragma unroll
    for (int j = 0; j < 4; ++j) {
        accv[0][0][j] = acc00[j]; accv[0][1][j] = acc01[j];
        accv[1][0][j] = acc10[j]; accv[1][1][j] = acc11[j];
    }

    if constexpr (MODE == 0 || MODE == 1) {
        __hip_bfloat16* O = (__hip_bfloat16*)outp;  // tiled [rows/16][128][16][4][8]
#pragma unroll
        for (int mf = 0; mf < 2; ++mf)
#pragma unroll
            for (int j = 0; j < 4; ++j) {
                int row = rb + mf * 16 + j;  // batch b (0..255)
                float v0 = 0.f, v1 = 0.f;
                if constexpr (MODE == 1) {
                    v0 = v[(size_t)(row * 100 + t) * 2 + 0];
                    v1 = v[(size_t)(row * 100 + t) * 2 + 1];
                }
#pragma unroll
                for (int nf = 0; nf < 2; ++nf) {
                    int col = cb + nf * 16;  // g index
                    float val = accv[mf][nf][j];
                    if constexpr (MODE == 1) {
                        val = fmaxf(val + v0 * Wi[col] + v1 * Wi[4096 + col], 0.0f);
                    }
                    size_t off = ((size_t)(row >> 4) * 128 + (col >> 5)) * 1024 +
                                 ((size_t)((row & 15) + (((col >> 3) & 3) << 4)) << 4) +
                                 ((col & 7) << 1);
                    union { __hip_bfloat16 h; short s; } u;
                    u.s = f2bf(val);
                    *(__hip_bfloat16*)((char*)O + off) = u.h;
                }
            }
    } else {
        float* O = (float*)outp;  // place_preds [256][100][512]
#pragma unroll
        for (int mf = 0; mf < 2; ++mf)
#pragma unroll
            for (int j = 0; j < 4; ++j) {
                int r = rb + mf * 16 + j;
                int tt = r >> 8;
                int b = r & 255;
#pragma unroll
                for (int nf = 0; nf < 2; ++nf) {
                    int c = cb + nf * 16;
                    O[((size_t)b * 100 + tt) * 512 + c] = accv[mf][nf][j];
                }
            }
    }
}

// ---------- launch ----------
extern "C" void kernel_launch(void* const* d_in, const int* in_sizes, int n_in,
                              void* d_out, int out_size, void* d_ws, size_t ws_size,
                              hipStream_t stream) {
    const float* v     = (const float*)d_in[0];  // [256][100][2]
    const float* P0    = (const float*)d_in[1];  // [256][512]
    const float* W_enc = (const float*)d_in[2];  // [512][4096]
    const float* W_in  = (const float*)d_in[3];  // [2][4096]
    const float* W_rec = (const float*)d_in[4];  // [4096][4096]
    const float* W_dec = (const float*)d_in[5];  // [4096][512]
    float* out = (float*)d_out;                  // [256][100][512]

    char* ws = (char*)d_ws;
    __hip_bfloat16* Wrt = (__hip_bfloat16*)(ws + 0);          // [4096][4096] = W_rec^T
    __hip_bfloat16* Wet = (__hip_bfloat16*)(ws + 33554432);   // [4096][512]  = W_enc^T
    __hip_bfloat16* Wdt = (__hip_bfloat16*)(ws + 37748736);   // [512][4096]  = W_dec^T
    __hip_bfloat16* P0t = (__hip_bfloat16*)(ws + 41943040);   // [256][512] tiled
    __hip_bfloat16* h0  = (__hip_bfloat16*)(ws + 42205184);   // [256][4096] tiled
    __hip_bfloat16* G   = (__hip_bfloat16*)(ws + 44302336);   // 100 x [256][4096] tiled slabs

    tcvt<<<dim3(64, 64), 256, 0, stream>>>(W_rec, Wrt, 4096, 4096);
    tcvt<<<dim3(8, 64), 256, 0, stream>>>(W_enc, Wet, 512, 4096);
    tcvt<<<dim3(64, 8), 256, 0, stream>>>(W_dec, Wdt, 4096, 512);
    cvt_tile<<<256, 64, 0, stream>>>(P0, P0t, 512);  // (256/16)*(512/32)=256 tiles

    // h0 = P0 @ W_enc
    gemm_k<0, 8><<<256, 256, 0, stream>>>(P0t, Wet, (void*)h0, nullptr, nullptr, 0);

    // recurrent steps
    for (int t = 0; t < 100; ++t) {
        const __hip_bfloat16* hprev = (t == 0) ? h0 : (G + (size_t)(t - 1) * 1048576);
        gemm_k<1, 64><<<256, 256, 0, stream>>>(hprev, Wrt,
                                               (void*)(G + (size_t)t * 1048576), v, W_in, t);
    }

    // decoder: tiled [25600][4096] @ Wdt^T -> d_out
    gemm_k<2, 64><<<3200, 256, 0, stream>>>(G, Wdt, (void*)out, nullptr, nullptr, 0);
}

// Round 6
// 1638.884 us; speedup vs baseline: 2.8823x; 1.6212x over previous
//
#include <hip/hip_runtime.h>
#include <hip/hip_bf16.h>

typedef __attribute__((ext_vector_type(8))) short bf16x8;
typedef __attribute__((ext_vector_type(4))) float f32x4;

#define MFMA __builtin_amdgcn_mfma_f32_16x16x32_bf16

// ---------- helpers ----------
__device__ __forceinline__ short f2bf(float f) {
    union { __hip_bfloat16 h; short s; } u;
    u.h = __float2bfloat16(f);
    return u.s;
}

__device__ __forceinline__ void gld_lds16(const void* g, void* l) {
    auto gp = (const __attribute__((address_space(1))) void*)(g);
    auto lp = (__attribute__((address_space(3))) void*)(l);
    __builtin_amdgcn_global_load_lds(gp, lp, 16, 0, 0);
}

// ---------- fp32 [R][C] -> MFMA-fragment-tiled bf16 (no transpose) ----------
// tile (r16, c32): lane l holds (row=l&15, k=(l>>4)*8+j) at tile*1024 + l*16 + j*2
__global__ __launch_bounds__(64) void cvt_tile(const float* __restrict__ in,
                                               __hip_bfloat16* __restrict__ out, int C) {
    const int cd32 = C >> 5;
    const int tile = blockIdx.x;
    const int r16 = tile / cd32, c32 = tile - r16 * cd32;
    const int l = threadIdx.x;
    const int row = (r16 << 4) + (l & 15);
    const int c0 = (c32 << 5) + ((l >> 4) << 3);
    const float* src = in + (size_t)row * C + c0;
    short o[8];
#pragma unroll
    for (int j = 0; j < 8; ++j) o[j] = f2bf(src[j]);
    *(bf16x8*)((char*)out + (size_t)tile * 1024 + (l << 4)) = *(bf16x8*)o;
}

// ---------- fp32 W[K][N] -> fragment-tiled bf16 of W^T (tiles over (n16, k32)) ----------
__global__ __launch_bounds__(64) void tcvt_tile(const float* __restrict__ in,
                                                __hip_bfloat16* __restrict__ out,
                                                int N, int K) {
    const int kd32 = K >> 5;
    const int tile = blockIdx.x;
    const int n16 = tile / kd32, k32 = tile - n16 * kd32;
    const int l = threadIdx.x;
    const int n = (n16 << 4) + (l & 15);
    const int k0 = (k32 << 5) + ((l >> 4) << 3);
    short o[8];
#pragma unroll
    for (int j = 0; j < 8; ++j) o[j] = f2bf(in[(size_t)(k0 + j) * N + n]);
    *(bf16x8*)((char*)out + (size_t)tile * 1024 + (l << 4)) = *(bf16x8*)o;
}

// ---------- per-wave K-split GEMM: C[M][N] = A @ B^T, tile 64x64 per block ----------
// Each of 4 waves owns the FULL 64x64 tile over a private K-quarter (KC k-steps of
// BK=32). Wave stages its own A(4KB)+B(4KB) sub-tiles into 4 private LDS buffers
// (global_load_lds, uniform 8-load groups, per-wave counted vmcnt(16) — NO barriers
// in the main loop). Operands are fragment-tiled in global, so LDS reads are
// identity-layout linear b128 (conflict-free). 4-way LDS reduction at the end.
// MODE 0: h0   (bf16 fragment-tiled out, NG=4096 cols)
// MODE 1: step (relu(acc + v0*Wi0[c] + v1*Wi1[c]) -> bf16 fragment-tiled out)
// MODE 2: decoder (fp32 out, row r -> t=r>>8, b=r&255 -> out[b][t][p])
template <int MODE, int KC>
__global__ __launch_bounds__(256, 1) void gemm_w(const __hip_bfloat16* __restrict__ A,
                                                 const __hip_bfloat16* __restrict__ B,
                                                 void* __restrict__ outp,
                                                 const float* __restrict__ v,
                                                 const float* __restrict__ Wi, int t) {
    constexpr int KD32 = KC * 4;  // K/32 total
    __shared__ __align__(16) char lds[131072];  // 4 waves x 4 bufs x 8KB
    const int id = blockIdx.x;
    int bm, bn;
    if constexpr (MODE == 2) {
        int xcd = id & 7, idx = id >> 3;
        int sw = xcd * 400 + idx;
        bm = sw >> 3;
        bn = sw & 7;
    } else {
        int xcd = id & 7, j = id >> 3;
        bn = (xcd << 3) + (j & 7);
        bm = j >> 3;
    }
    const int tid = threadIdx.x, wv = tid >> 6, lane = tid & 63;
    char* myl = lds + (wv << 15);
    const int kw0 = wv * KC;         // this wave's first k32 tile
    const int bm4 = bm << 2, bn4 = bn << 2;

    f32x4 acc[4][4] = {};

    auto stage = [&](int s) {
        char* dst = myl + ((s & 3) << 13);
#pragma unroll
        for (int f = 0; f < 4; ++f) {
            gld_lds16((const char*)A + ((size_t)((bm4 + f) * KD32 + kw0 + s) << 10) + (lane << 4),
                      dst + (f << 10));
            gld_lds16((const char*)B + ((size_t)((bn4 + f) * KD32 + kw0 + s) << 10) + (lane << 4),
                      dst + 4096 + (f << 10));
        }
    };

#define KSTEP(S, DOST)                                                       \
    {                                                                        \
        const char* buf_ = myl + (((S) & 3) << 13);                          \
        bf16x8 a_[4], b_[4];                                                 \
        _Pragma("unroll") for (int f = 0; f < 4; ++f) {                      \
            a_[f] = *(const bf16x8*)(buf_ + (f << 10) + (lane << 4));        \
            b_[f] = *(const bf16x8*)(buf_ + 4096 + (f << 10) + (lane << 4)); \
        }                                                                    \
        if (DOST) stage((S) + 3);                                            \
        _Pragma("unroll") for (int f = 0; f < 4; ++f)                        \
            _Pragma("unroll") for (int g = 0; g < 4; ++g)                    \
                acc[f][g] = MFMA(a_[f], b_[g], acc[f][g], 0, 0, 0);          \
    }

    // prologue: 3 pinned uniform groups of 8 global_load_lds each
    stage(0);
    __builtin_amdgcn_sched_barrier(0);
    stage(1);
    __builtin_amdgcn_sched_barrier(0);
    stage(2);
    __builtin_amdgcn_sched_barrier(0);

    for (int s = 0; s < KC - 2; ++s) {
        asm volatile("s_waitcnt vmcnt(16)" ::: "memory");
        __builtin_amdgcn_sched_barrier(0);
        KSTEP(s, s + 3 < KC);
    }
    asm volatile("s_waitcnt vmcnt(8)" ::: "memory");
    __builtin_amdgcn_sched_barrier(0);
    KSTEP(KC - 2, false);
    asm volatile("s_waitcnt vmcnt(0)" ::: "memory");
    __builtin_amdgcn_sched_barrier(0);
    KSTEP(KC - 1, false);
#undef KSTEP

    // ---- cross-wave K-reduction via LDS ----
    __syncthreads();  // all waves done with their buffers
#pragma unroll
    for (int f = 0; f < 4; ++f)
#pragma unroll
        for (int g = 0; g < 4; ++g)
            *(f32x4*)(lds + (wv << 14) + (((f << 2) + g) << 10) + (lane << 4)) = acc[f][g];
    __syncthreads();
    f32x4 fin[4];
#pragma unroll
    for (int g = 0; g < 4; ++g) {
        f32x4 s0 = *(const f32x4*)(lds + (0 << 14) + ((((wv << 2) + g)) << 10) + (lane << 4));
        f32x4 s1 = *(const f32x4*)(lds + (1 << 14) + ((((wv << 2) + g)) << 10) + (lane << 4));
        f32x4 s2 = *(const f32x4*)(lds + (2 << 14) + ((((wv << 2) + g)) << 10) + (lane << 4));
        f32x4 s3 = *(const f32x4*)(lds + (3 << 14) + ((((wv << 2) + g)) << 10) + (lane << 4));
        fin[g] = (s0 + s1) + (s2 + s3);
    }

    // ---- epilogue: wave wv owns rows [bm*64 + wv*16, +16) of the tile ----
    const int rbase = (bm << 6) + (wv << 4) + ((lane >> 4) << 2);
    const int cbase = (bn << 6) + (lane & 15);

    if constexpr (MODE == 0 || MODE == 1) {
        char* O = (char*)outp;  // fragment-tiled [rows/16][128][64 lanes][16B]
#pragma unroll
        for (int j = 0; j < 4; ++j) {
            int r = rbase + j;
            float v0 = 0.f, v1 = 0.f;
            if constexpr (MODE == 1) {
                v0 = v[(size_t)(r * 100 + t) * 2 + 0];
                v1 = v[(size_t)(r * 100 + t) * 2 + 1];
            }
#pragma unroll
            for (int g = 0; g < 4; ++g) {
                int c = cbase + (g << 4);
                float val = fin[g][j];
                if constexpr (MODE == 1) {
                    val = fmaxf(val + v0 * Wi[c] + v1 * Wi[4096 + c], 0.0f);
                }
                size_t off = ((size_t)(r >> 4) * 128 + (c >> 5)) * 1024 +
                             ((size_t)((r & 15) + (((c >> 3) & 3) << 4)) << 4) +
                             ((c & 7) << 1);
                *(short*)(O + off) = f2bf(val);
            }
        }
    } else {
        float* O = (float*)outp;  // place_preds [256][100][512]
#pragma unroll
        for (int j = 0; j < 4; ++j) {
            int r = rbase + j;
            int tt = r >> 8;
            int b = r & 255;
#pragma unroll
            for (int g = 0; g < 4; ++g) {
                int c = cbase + (g << 4);
                O[((size_t)b * 100 + tt) * 512 + c] = fin[g][j];
            }
        }
    }
}

// ---------- launch ----------
extern "C" void kernel_launch(void* const* d_in, const int* in_sizes, int n_in,
                              void* d_out, int out_size, void* d_ws, size_t ws_size,
                              hipStream_t stream) {
    const float* v     = (const float*)d_in[0];  // [256][100][2]
    const float* P0    = (const float*)d_in[1];  // [256][512]
    const float* W_enc = (const float*)d_in[2];  // [512][4096]
    const float* W_in  = (const float*)d_in[3];  // [2][4096]
    const float* W_rec = (const float*)d_in[4];  // [4096][4096]
    const float* W_dec = (const float*)d_in[5];  // [4096][512]
    float* out = (float*)d_out;                  // [256][100][512]

    char* ws = (char*)d_ws;
    __hip_bfloat16* Wrt = (__hip_bfloat16*)(ws + 0);          // W_rec^T tiled [256][128] tiles
    __hip_bfloat16* Wet = (__hip_bfloat16*)(ws + 33554432);   // W_enc^T tiled [256][16]
    __hip_bfloat16* Wdt = (__hip_bfloat16*)(ws + 37748736);   // W_dec^T tiled [32][128]
    __hip_bfloat16* P0t = (__hip_bfloat16*)(ws + 41943040);   // P0 tiled [16][16]
    __hip_bfloat16* h0  = (__hip_bfloat16*)(ws + 42205184);   // h0 tiled [16][128]
    __hip_bfloat16* G   = (__hip_bfloat16*)(ws + 44302336);   // 100 slabs, each tiled [16][128]

    tcvt_tile<<<32768, 64, 0, stream>>>(W_rec, Wrt, 4096, 4096);  // (4096/16)*(4096/32)
    tcvt_tile<<<4096, 64, 0, stream>>>(W_enc, Wet, 4096, 512);    // (4096/16)*(512/32)
    tcvt_tile<<<4096, 64, 0, stream>>>(W_dec, Wdt, 512, 4096);    // (512/16)*(4096/32)
    cvt_tile<<<256, 64, 0, stream>>>(P0, P0t, 512);               // (256/16)*(512/32)

    // h0 = P0 @ W_enc   (K=512 -> KC=4)
    gemm_w<0, 4><<<256, 256, 0, stream>>>(P0t, Wet, (void*)h0, nullptr, nullptr, 0);

    // recurrent steps (K=4096 -> KC=32)
    for (int t = 0; t < 100; ++t) {
        const __hip_bfloat16* hprev = (t == 0) ? h0 : (G + (size_t)(t - 1) * 1048576);
        gemm_w<1, 32><<<256, 256, 0, stream>>>(hprev, Wrt,
                                               (void*)(G + (size_t)t * 1048576), v, W_in, t);
    }

    // decoder: [25600][4096] tiled @ Wdt -> d_out
    gemm_w<2, 32><<<3200, 256, 0, stream>>>(G, Wdt, (void*)out, nullptr, nullptr, 0);
}